// Round 5
// baseline (336.969 us; speedup 1.0000x reference)
//
#include <hip/hip_runtime.h>
#include <hip/hip_bf16.h>

#define BB 4
#define TT 2048
#define DD 1024
#define NHEAD 16
#define HDIM 64
#define NKT 16   // K / 64

typedef __bf16 v8bf __attribute__((ext_vector_type(8)));
typedef __bf16 v4bf __attribute__((ext_vector_type(4)));
typedef float  v4f  __attribute__((ext_vector_type(4)));

// (1/32) * log2(e): folded into Q projection epilogue
#define C2SCALE 0.04508422376f

__device__ __forceinline__ void gl2lds16(const void* g, void* l) {
  __builtin_amdgcn_global_load_lds(
      (__attribute__((address_space(1))) const void*)g,
      (__attribute__((address_space(3))) void*)l, 16, 0, 0);
}

// ---------------------------------------------------------------------------
// prep: grid 2560.
//   blocks 0..1535:   fp32->bf16 casts, 8 x (256x8-elem) units per block
//   blocks 1536..2559: 4 weight transposes, 64x64 tiles
// ---------------------------------------------------------------------------
__global__ __launch_bounds__(256) void prep(
    const float* __restrict__ qsrc, const float* __restrict__ ksrc,
    const float* __restrict__ vsrc,
    const float* __restrict__ w0, const float* __restrict__ w1,
    const float* __restrict__ w2, const float* __restrict__ w3,
    __bf16* __restrict__ qdst, __bf16* __restrict__ kdst,
    __bf16* __restrict__ vdst,
    __bf16* __restrict__ t0, __bf16* __restrict__ t1,
    __bf16* __restrict__ t2, __bf16* __restrict__ t3) {
  constexpr int STR = 72;
  __shared__ __bf16 sh[64 * STR];
  int bx = blockIdx.x, tid = threadIdx.x;
  if (bx < 1536) {
    int z = bx >> 9, ib = bx & 511;
    const float* src = z == 0 ? qsrc : z == 1 ? ksrc : vsrc;
    __bf16* dst = z == 0 ? qdst : z == 1 ? kdst : vdst;
#pragma unroll
    for (int k = 0; k < 8; ++k) {
      int u = ib * 2048 + k * 256 + tid;           // 8-elem unit
      const float4* s = (const float4*)src + (size_t)u * 2;
      float4 f0 = s[0], f1 = s[1];
      v8bf v;
      v[0] = (__bf16)f0.x; v[1] = (__bf16)f0.y; v[2] = (__bf16)f0.z; v[3] = (__bf16)f0.w;
      v[4] = (__bf16)f1.x; v[5] = (__bf16)f1.y; v[6] = (__bf16)f1.z; v[7] = (__bf16)f1.w;
      *(v8bf*)(dst + (size_t)u * 8) = v;
    }
  } else {
    int idx = bx - 1536;
    int z = idx >> 8;
    const float* W = z == 0 ? w0 : z == 1 ? w1 : z == 2 ? w2 : w3;
    __bf16* Wt = z == 0 ? t0 : z == 1 ? t1 : z == 2 ? t2 : t3;
    int n0 = (idx & 15) * 64, k0 = ((idx >> 4) & 15) * 64;
#pragma unroll
    for (int p = 0; p < 4; ++p) {
      int c = tid + p * 256;
      int r = c >> 4, off = (c & 15) * 4;
      float4 f = *(const float4*)(W + (size_t)(k0 + r) * DD + n0 + off);
      __bf16* d = &sh[r * STR + off];
      d[0] = (__bf16)f.x; d[1] = (__bf16)f.y; d[2] = (__bf16)f.z; d[3] = (__bf16)f.w;
    }
    __syncthreads();
#pragma unroll
    for (int p = 0; p < 2; ++p) {
      int c = tid + p * 256;
      int nr = c >> 3, koff = (c & 7) * 8;
      v8bf v;
#pragma unroll
      for (int j = 0; j < 8; ++j) v[j] = sh[(koff + j) * STR + nr];
      *(v8bf*)(Wt + (size_t)(n0 + nr) * DD + k0 + koff) = v;
    }
  }
}

// ---------------------------------------------------------------------------
// 8-phase 256x256 GEMM for QKV (BK=64, 512 thr = 8 waves 2M x 4N, 128KB LDS).
// CORRECTED WAITS vs R1 (R1 over-waited vmcnt(6) every phase = full-latency
// stall per phase; and under-waited the prologue).  Dependency ledger:
//   stage at tile j: p1->A1(j+1), p2->B1(j+1), p3->A0(j+2), p4->B0(j+2)
//   tile j+1 reads need completion through j p2.
//   At j p4: outstanding = {j-1 p3,p4, j p1..p4} = 12 loads; vmcnt(4) drains
//   the oldest 8 = exactly through j p2.  Phases 1-3: NO vm wait.
//   Prologue (12 loads): vmcnt(4) completes tile-0's 4 halves.
//   Tile 14: vmcnt(0) (staging stopped; tile-15 halves from 14 p1/p2).
// ---------------------------------------------------------------------------
__global__ __launch_bounds__(512, 2) void gemm8p(
    const __bf16* __restrict__ A0p, const __bf16* __restrict__ A1p,
    const __bf16* __restrict__ A2p,
    const __bf16* __restrict__ W0p, const __bf16* __restrict__ W1p,
    const __bf16* __restrict__ W2p,
    const float* __restrict__ b0p, const float* __restrict__ b1p,
    const float* __restrict__ b2p,
    __bf16* __restrict__ Qp, __bf16* __restrict__ Kp,
    __bf16* __restrict__ VTb) {
  extern __shared__ __bf16 lds[];  // [2 bufs][A 16384 | B 16384] elems = 128KB
  int tid = threadIdx.x, wave = tid >> 6, lane = tid & 63;
  int quad = lane >> 4, l15 = lane & 15, swz = l15 & 7;
  int wm2 = wave >> 2, wn4 = wave & 3;
  int lin = blockIdx.x;
  int qx = gridDim.x >> 3;                    // blocks per XCD chunk
  int wg = (lin >> 3) + (lin & 7) * qx;       // bijective XCD chunking (384%8==0)
  int z = wg >> 7, t = wg & 127;              // 128 tiles per z (32m x 4n)
  int m0 = (t >> 2) * 256, n0 = (t & 3) * 256;
  const __bf16* __restrict__ A  = z == 0 ? A0p : z == 1 ? A1p : A2p;
  const __bf16* __restrict__ Wt = z == 0 ? W0p : z == 1 ? W1p : W2p;
  const float* __restrict__ bias = z == 0 ? b0p : z == 1 ? b1p : b2p;

  v4f acc[8][4];
#pragma unroll
  for (int mi = 0; mi < 8; ++mi)
#pragma unroll
    for (int ni = 0; ni < 4; ++ni) acc[mi][ni] = (v4f){0.f, 0.f, 0.f, 0.f};

#define STAGE(XP, x0, base, h, kt) do {                                     \
  int k0s = (kt) * 64;                                                      \
_Pragma("unroll")                                                           \
  for (int w = 0; w < 2; ++w) {                                             \
    int idx = w * 512 + tid;                                                \
    int srow = (h) * 128 + (idx >> 3);                                      \
    int g = (idx & 7) ^ (srow & 7);                                         \
    gl2lds16((XP) + (size_t)((x0) + srow) * DD + k0s + g * 8,               \
             lds + (base) + (h) * 8192 + idx * 8);                          \
  }                                                                         \
} while (0)

#define LD_A(d, mh) do {                                                    \
_Pragma("unroll")                                                           \
  for (int ks = 0; ks < 2; ++ks)                                            \
_Pragma("unroll")                                                           \
    for (int jm = 0; jm < 4; ++jm)                                          \
      afr[ks][jm] = *(const v8bf*)&lds[(d) * 32768 +                        \
          (wm2 * 64 + (mh) * 128 + jm * 16 + l15) * 64 +                    \
          ((ks * 4 + quad) ^ swz) * 8];                                     \
} while (0)

#define LD_B(d, nh) do {                                                    \
_Pragma("unroll")                                                           \
  for (int ks = 0; ks < 2; ++ks)                                            \
_Pragma("unroll")                                                           \
    for (int jn = 0; jn < 2; ++jn)                                          \
      bfr[nh][ks][jn] = *(const v8bf*)&lds[(d) * 32768 + 16384 +            \
          (wn4 * 32 + (nh) * 128 + jn * 16 + l15) * 64 +                    \
          ((ks * 4 + quad) ^ swz) * 8];                                     \
} while (0)

// phases 1-3: barrier, wait own ds_reads only — NO vm wait
#define SYNC_PH() do {                                                      \
  __builtin_amdgcn_s_barrier();                                             \
  asm volatile("s_waitcnt lgkmcnt(0)" ::: "memory");                        \
} while (0)

// phase 4: counted vm wait (once per K-tile), then barrier
#define SYNC_P4(VM) do {                                                    \
  asm volatile("s_waitcnt vmcnt(" #VM ")" ::: "memory");                    \
  __builtin_amdgcn_s_barrier();                                             \
  asm volatile("s_waitcnt lgkmcnt(0)" ::: "memory");                        \
} while (0)

#define MFMA16(mh, nh) do {                                                 \
  __builtin_amdgcn_s_setprio(1);                                            \
_Pragma("unroll")                                                           \
  for (int ks = 0; ks < 2; ++ks)                                            \
_Pragma("unroll")                                                           \
    for (int jm = 0; jm < 4; ++jm)                                          \
_Pragma("unroll")                                                           \
      for (int jn = 0; jn < 2; ++jn)                                        \
        acc[(mh) * 4 + jm][(nh) * 2 + jn] =                                 \
            __builtin_amdgcn_mfma_f32_16x16x32_bf16(                        \
                afr[ks][jm], bfr[nh][ks][jn],                               \
                acc[(mh) * 4 + jm][(nh) * 2 + jn], 0, 0, 0);                \
  __builtin_amdgcn_s_setprio(0);                                            \
  __builtin_amdgcn_s_barrier();                                             \
} while (0)

#define TILE(d, jt, VM4) do {                                               \
  v8bf afr[2][4]; v8bf bfr[2][2][2];                                        \
  /* phase 1: (mh=0,nh=0) */                                                \
  LD_A(d, 0); LD_B(d, 0);                                                   \
  if ((jt) + 1 < NKT) STAGE(A, m0, ((d) ^ 1) * 32768, 1, (jt) + 1);         \
  SYNC_PH(); MFMA16(0, 0);                                                  \
  /* phase 2: (0,1) */                                                      \
  LD_B(d, 1);                                                               \
  if ((jt) + 1 < NKT) STAGE(Wt, n0, ((d) ^ 1) * 32768 + 16384, 1, (jt) + 1);\
  SYNC_PH(); MFMA16(0, 1);                                                  \
  /* phase 3: (1,0) */                                                      \
  LD_A(d, 1);                                                               \
  if ((jt) + 2 < NKT) STAGE(A, m0, (d) * 32768, 0, (jt) + 2);               \
  SYNC_PH(); MFMA16(1, 0);                                                  \
  /* phase 4: (1,1) — the ONE counted vm wait per K-tile */                 \
  if ((jt) + 2 < NKT) STAGE(Wt, n0, (d) * 32768 + 16384, 0, (jt) + 2);      \
  SYNC_P4(VM4); MFMA16(1, 1);                                               \
} while (0)

  // prologue: tile 0 complete + half0 of tile 1  (12 loads/thread)
  STAGE(A, m0, 0, 0, 0);          // A0(0)
  STAGE(Wt, n0, 16384, 0, 0);     // B0(0)
  STAGE(A, m0, 0, 1, 0);          // A1(0)
  STAGE(Wt, n0, 16384, 1, 0);     // B1(0)
  STAGE(A, m0, 32768, 0, 1);      // A0(1)
  STAGE(Wt, n0, 32768 + 16384, 0, 1);  // B0(1)
  asm volatile("s_waitcnt vmcnt(4)" ::: "memory");  // all 4 halves of tile 0
  __builtin_amdgcn_s_barrier();

  for (int j2 = 0; j2 < 7; ++j2) {
    TILE(0, j2 * 2, 4);
    TILE(1, j2 * 2 + 1, 4);
  }
  TILE(0, 14, 0);   // drain: tile-15 halves staged at 14 p1/p2
  TILE(1, 15, 0);

  // epilogue (proven in R1)
#pragma unroll
  for (int ni = 0; ni < 4; ++ni) {
    int col = n0 + wn4 * 32 + (ni >> 1) * 128 + (ni & 1) * 16 + l15;
    float bv = bias[col];
    if (z == 2) {  // V: write transposed per-head [bh][d][t]
      int b = m0 >> 11;
      __bf16* rowp = VTb + ((size_t)(b * 16 + (col >> 6)) * 64 + (col & 63)) * TT;
      int tb0 = (m0 & 2047) + wm2 * 64;
#pragma unroll
      for (int mi = 0; mi < 8; ++mi) {
        int tb = tb0 + (mi >> 2) * 128 + (mi & 3) * 16 + quad * 4;
        v4bf o;
#pragma unroll
        for (int r = 0; r < 4; ++r) o[r] = (__bf16)(acc[mi][ni][r] + bv);
        *(v4bf*)(rowp + tb) = o;
      }
    } else {  // Q (with C2SCALE folded) or K
      __bf16* C = z == 0 ? Qp : Kp;
      float scale = z == 0 ? C2SCALE : 1.0f;
#pragma unroll
      for (int mi = 0; mi < 8; ++mi) {
        int row = m0 + wm2 * 64 + (mi >> 2) * 128 + (mi & 3) * 16 + quad * 4;
#pragma unroll
        for (int r = 0; r < 4; ++r)
          C[(size_t)(row + r) * DD + col] = (__bf16)((acc[mi][ni][r] + bv) * scale);
      }
    }
  }
#undef TILE
#undef MFMA16
#undef SYNC_P4
#undef SYNC_PH
#undef LD_B
#undef LD_A
#undef STAGE
}

// ---------------------------------------------------------------------------
// Proven 2-barrier 128² GEMM core (for gemm_out only).
// ---------------------------------------------------------------------------
__device__ __forceinline__ void gemm_core(const __bf16* __restrict__ A,
                                          const __bf16* __restrict__ Wt,
                                          int m0, int n0,
                                          __bf16* ash, __bf16* bsh,
                                          int wave, int lane, int quad, int l15,
                                          v4f acc[4][4]) {
  int wm = (wave & 1) * 64, wn = (wave >> 1) * 64;
  for (int k0 = 0; k0 < DD; k0 += 64) {
    __syncthreads();
#pragma unroll
    for (int i = 0; i < 4; ++i) {
      int c = wave * 256 + i * 64 + lane;
      int row = c >> 3, g = (c & 7) ^ (row & 7);
      gl2lds16(A + (size_t)(m0 + row) * DD + k0 + g * 8, ash + wave * 2048 + i * 512);
      gl2lds16(Wt + (size_t)(n0 + row) * DD + k0 + g * 8, bsh + wave * 2048 + i * 512);
    }
    __syncthreads();
#pragma unroll
    for (int ks = 0; ks < 2; ++ks) {
      int sw = (((ks * 4 + quad) ^ (l15 & 7))) * 8;
      v8bf a[4], b[4];
#pragma unroll
      for (int jm = 0; jm < 4; ++jm) a[jm] = *(v8bf*)&ash[(wm + jm * 16 + l15) * 64 + sw];
#pragma unroll
      for (int jn = 0; jn < 4; ++jn) b[jn] = *(v8bf*)&bsh[(wn + jn * 16 + l15) * 64 + sw];
#pragma unroll
      for (int jm = 0; jm < 4; ++jm)
#pragma unroll
        for (int jn = 0; jn < 4; ++jn)
          acc[jm][jn] = __builtin_amdgcn_mfma_f32_16x16x32_bf16(a[jm], b[jn], acc[jm][jn], 0, 0, 0);
    }
  }
}

// XCD-aware tile swizzle: the 8 blocks sharing an m-panel get lin%8==c -> one XCD.
__device__ __forceinline__ void swz_tiles(int& m0, int& n0) {
  int lin = blockIdx.x + 8 * blockIdx.y;
  int c = lin & 7, t = lin >> 3;
  n0 = (t & 7) * 128;
  m0 = (c + ((t >> 3) << 3)) * 128;
}

// ---------------------------------------------------------------------------
// Output GEMM: out = Ab @ woT^T + wo_b (fp32). grid (8,64).  (proven R0)
// ---------------------------------------------------------------------------
__global__ __launch_bounds__(256) void gemm_out(const __bf16* __restrict__ A,
                                                const __bf16* __restrict__ Wt,
                                                const float* __restrict__ bias,
                                                float* __restrict__ C) {
  __shared__ __bf16 ash[128 * 64];
  __shared__ __bf16 bsh[128 * 64];
  int tid = threadIdx.x, wave = tid >> 6, lane = tid & 63;
  int quad = lane >> 4, l15 = lane & 15;
  int m0, n0;
  swz_tiles(m0, n0);
  int wm = (wave & 1) * 64, wn = (wave >> 1) * 64;
  v4f acc[4][4];
#pragma unroll
  for (int jm = 0; jm < 4; ++jm)
#pragma unroll
    for (int jn = 0; jn < 4; ++jn) acc[jm][jn] = (v4f){0.f, 0.f, 0.f, 0.f};

  gemm_core(A, Wt, m0, n0, ash, bsh, wave, lane, quad, l15, acc);

#pragma unroll
  for (int jn = 0; jn < 4; ++jn) {
    int col = n0 + wn + jn * 16 + l15;
    float bv = bias[col];
#pragma unroll
    for (int jm = 0; jm < 4; ++jm) {
#pragma unroll
      for (int r = 0; r < 4; ++r) {
        int row = m0 + wm + jm * 16 + quad * 4 + r;
        C[(size_t)row * DD + col] = acc[jm][jn][r] + bv;
      }
    }
  }
}

// ---------------------------------------------------------------------------
// Flash attention (verbatim Round-4: causal, transposed-softmax, balanced
// pairing, XCD head placement, dbuf K/V staging, lr via ones-MFMA, setprio).
// grid: (8, 64)
// ---------------------------------------------------------------------------
__global__ __launch_bounds__(256) void attn_bal(const __bf16* __restrict__ Q,
                                                const __bf16* __restrict__ K,
                                                const __bf16* __restrict__ VT,
                                                __bf16* __restrict__ O) {
  __shared__ __bf16 ksh[2][64 * 64];
  __shared__ __bf16 vsh[2][64 * 64];       // vsh[d][t]
  __shared__ __bf16 psh[128 * 64];         // Q staging / P^T, XOR-swizzled
  int tid = threadIdx.x, wave = tid >> 6, lane = tid & 63;
  int quad = lane >> 4, l15 = lane & 15;
  int swz = l15 & 7;
  int lin = blockIdx.x + 8 * blockIdx.y;
  int c = lin & 7, t = lin >> 3;
  int xq = t & 7;                     // q-pair index 0..7
  int bh = c + ((t >> 3) << 3);       // head-group 0..63
  int b = bh >> 4, h = bh & 15;
  const __bf16* Qb = Q + (size_t)(b * TT) * DD + h * HDIM;
  const __bf16* Kb = K + (size_t)(b * TT) * DD + h * HDIM;
  const __bf16* Vb = VT + (size_t)bh * HDIM * TT;
  __bf16* Ob = O + (size_t)(b * TT) * DD + h * HDIM;

  v8bf ones;
#pragma unroll
  for (int j = 0; j < 8; ++j) ones[j] = (__bf16)1.0f;

  for (int phase = 0; phase < 2; ++phase) {
    int qi = phase ? 15 - xq : xq;
    int q0 = qi * 128;
    int ktiles = 2 * qi + 2;

#pragma unroll
    for (int i = 0; i < 4; ++i) {
      int cc = wave * 256 + i * 64 + lane;
      int row = cc >> 3, g = (cc & 7) ^ (row & 7);
      gl2lds16(Qb + (size_t)(q0 + row) * DD + g * 8, psh + wave * 2048 + i * 512);
    }
#pragma unroll
    for (int i = 0; i < 2; ++i) {
      int cc = wave * 128 + i * 64 + lane;
      int row = cc >> 3, g = (cc & 7) ^ (row & 7);
      gl2lds16(Kb + (size_t)row * DD + g * 8, &ksh[0][wave * 1024 + i * 512]);
      gl2lds16(Vb + (size_t)row * TT + g * 8, &vsh[0][wave * 1024 + i * 512]);
    }
    __builtin_amdgcn_s_waitcnt(0);
    __syncthreads();

    v8bf qf[2][2];
#pragma unroll
    for (int set = 0; set < 2; ++set)
#pragma unroll
      for (int ks = 0; ks < 2; ++ks)
        qf[set][ks] = *(v8bf*)&psh[(wave * 32 + set * 16 + l15) * 64 + ((ks * 4 + quad) ^ swz) * 8];

    int qg[2] = {q0 + wave * 32 + l15, q0 + wave * 32 + 16 + l15};
    v4f oacc[2][4], lracc[2];
#pragma unroll
    for (int set = 0; set < 2; ++set) {
      lracc[set] = (v4f){0.f, 0.f, 0.f, 0.f};
#pragma unroll
      for (int jm = 0; jm < 4; ++jm) oacc[set][jm] = (v4f){0.f, 0.f, 0.f, 0.f};
    }

    int pbuf = 0;
    for (int kt = 0; kt < ktiles; ++kt) {
      if (kt + 1 < ktiles) {
        int k0n = (kt + 1) * 64;
#pragma unroll
        for (int i = 0; i < 2; ++i) {
          int cc = wave * 128 + i * 64 + lane;
          int row = cc >> 3, g = (cc & 7) ^ (row & 7);
          gl2lds16(Kb + (size_t)(k0n + row) * DD + g * 8, &ksh[pbuf ^ 1][wave * 1024 + i * 512]);
          gl2lds16(Vb + (size_t)row * TT + k0n + g * 8, &vsh[pbuf ^ 1][wave * 1024 + i * 512]);
        }
      }
      int k0 = kt * 64;
      const __bf16* kshp = &ksh[pbuf][0];
      const __bf16* vshp = &vsh[pbuf][0];

      v4f s[2][4];
#pragma unroll
      for (int set = 0; set < 2; ++set)
#pragma unroll
        for (int jf = 0; jf < 4; ++jf) s[set][jf] = (v4f){0.f, 0.f, 0.f, 0.f};
      __builtin_amdgcn_s_setprio(1);
#pragma unroll
      for (int ks = 0; ks < 2; ++ks) {
        int sw = ((ks * 4 + quad) ^ swz) * 8;
#pragma unroll
        for (int jf = 0; jf < 4; ++jf) {
          v8bf kf = *(v8bf*)&kshp[(jf * 16 + l15) * 64 + sw];
          s[0][jf] = __builtin_amdgcn_mfma_f32_16x16x32_bf16(kf, qf[0][ks], s[0][jf], 0, 0, 0);
          s[1][jf] = __builtin_amdgcn_mfma_f32_16x16x32_bf16(kf, qf[1][ks], s[1][jf], 0, 0, 0);
        }
      }
      __builtin_amdgcn_s_setprio(0);

      bool diag = (kt >= 2 * qi);
#pragma unroll
      for (int set = 0; set < 2; ++set) {
        int qrow = wave * 32 + set * 16 + l15;
        __bf16* prow = &psh[qrow * 64];
#pragma unroll
        for (int jf = 0; jf < 4; ++jf) {
          v4bf pk;
#pragma unroll
          for (int r = 0; r < 4; ++r) {
            float p = __builtin_amdgcn_exp2f(s[set][jf][r]);
            if (diag) {
              int kg = k0 + jf * 16 + quad * 4 + r;
              if (kg > qg[set]) p = 0.f;
            }
            pk[r] = (__bf16)p;
          }
          int chunk = jf * 2 + (quad >> 1);
          *(v4bf*)&prow[(chunk ^ swz) * 8 + (quad & 1) * 4] = pk;
        }
      }

      __builtin_amdgcn_s_setprio(1);
#pragma unroll
      for (int ks = 0; ks < 2; ++ks) {
        int sw = ((ks * 4 + quad) ^ swz) * 8;
        v8bf pb0 = *(v8bf*)&psh[(wave * 32 + l15) * 64 + sw];
        v8bf pb1 = *(v8bf*)&psh[(wave * 32 + 16 + l15) * 64 + sw];
        lracc[0] = __builtin_amdgcn_mfma_f32_16x16x32_bf16(ones, pb0, lracc[0], 0, 0, 0);
        lracc[1] = __builtin_amdgcn_mfma_f32_16x16x32_bf16(ones, pb1, lracc[1], 0, 0, 0);
#pragma unroll
        for (int jm = 0; jm < 4; ++jm) {
          v8bf vf = *(v8bf*)&vshp[(jm * 16 + l15) * 64 + sw];
          oacc[0][jm] = __builtin_amdgcn_mfma_f32_16x16x32_bf16(vf, pb0, oacc[0][jm], 0, 0, 0);
          oacc[1][jm] = __builtin_amdgcn_mfma_f32_16x16x32_bf16(vf, pb1, oacc[1][jm], 0, 0, 0);
        }
      }
      __builtin_amdgcn_s_setprio(0);

      __builtin_amdgcn_s_waitcnt(0);
      __syncthreads();
      pbuf ^= 1;
    }

#pragma unroll
    for (int set = 0; set < 2; ++set) {
      float inv = 1.0f / lracc[set][0];
      int q = q0 + wave * 32 + set * 16 + l15;
#pragma unroll
      for (int jm = 0; jm < 4; ++jm) {
        v4bf o;
#pragma unroll
        for (int r = 0; r < 4; ++r) o[r] = (__bf16)(oacc[set][jm][r] * inv);
        *(v4bf*)(Ob + (size_t)q * DD + jm * 16 + quad * 4) = o;
      }
    }
  }
}

// ---------------------------------------------------------------------------
extern "C" void kernel_launch(void* const* d_in, const int* in_sizes, int n_in,
                              void* d_out, int out_size, void* d_ws, size_t ws_size,
                              hipStream_t stream) {
  const float* query = (const float*)d_in[0];
  const float* key_  = (const float*)d_in[1];
  const float* value = (const float*)d_in[2];
  const float* wq_w = (const float*)d_in[3];
  const float* wq_b = (const float*)d_in[4];
  const float* wk_w = (const float*)d_in[5];
  const float* wk_b = (const float*)d_in[6];
  const float* wv_w = (const float*)d_in[7];
  const float* wv_b = (const float*)d_in[8];
  const float* wo_w = (const float*)d_in[9];
  const float* wo_b = (const float*)d_in[10];

  char* ws = (char*)d_ws;
  const size_t MB = (size_t)1 << 20;
  __bf16* wqT = (__bf16*)(ws + 0 * MB);
  __bf16* wkT = (__bf16*)(ws + 2 * MB);
  __bf16* wvT = (__bf16*)(ws + 4 * MB);
  __bf16* woT = (__bf16*)(ws + 6 * MB);
  __bf16* Qc  = (__bf16*)(ws + 8 * MB);    // cast inputs (later reused)
  __bf16* Kc  = (__bf16*)(ws + 24 * MB);
  __bf16* Vc  = (__bf16*)(ws + 40 * MB);
  __bf16* Qp  = (__bf16*)(ws + 56 * MB);
  __bf16* Kp  = (__bf16*)(ws + 72 * MB);
  __bf16* VTb = (__bf16*)(ws + 88 * MB);   // peak 104 MB
  __bf16* Ab  = (__bf16*)(ws + 8 * MB);    // reuse Qc
  float* out = (float*)d_out;

  static int attr_done = 0;
  if (!attr_done) {
    hipFuncSetAttribute((const void*)gemm8p,
                        hipFuncAttributeMaxDynamicSharedMemorySize, 131072);
    attr_done = 1;
  }

  dim3 tb(256);
  prep<<<dim3(2560), tb, 0, stream>>>(query, key_, value, wq_w, wk_w, wv_w, wo_w,
                                      Qc, Kc, Vc, wqT, wkT, wvT, woT);
  gemm8p<<<dim3(384), dim3(512), 131072, stream>>>(
      Qc, Kc, Vc, wqT, wkT, wvT, wq_b, wk_b, wv_b, Qp, Kp, VTb);
  attn_bal<<<dim3(8, 64), tb, 0, stream>>>(Qp, Kp, VTb, Ab);
  gemm_out<<<dim3(8, 64), tb, 0, stream>>>(Ab, woT, wo_b, out);
}

// Round 6
// 321.344 us; speedup vs baseline: 1.0486x; 1.0486x over previous
//
#include <hip/hip_runtime.h>
#include <hip/hip_bf16.h>

#define BB 4
#define TT 2048
#define DD 1024
#define NHEAD 16
#define HDIM 64

typedef __bf16 v8bf __attribute__((ext_vector_type(8)));
typedef __bf16 v4bf __attribute__((ext_vector_type(4)));
typedef float  v4f  __attribute__((ext_vector_type(4)));

// (1/32) * log2(e): folded into Q projection epilogue
#define C2SCALE 0.04508422376f

__device__ __forceinline__ void gl2lds16(const void* g, void* l) {
  __builtin_amdgcn_global_load_lds(
      (__attribute__((address_space(1))) const void*)g,
      (__attribute__((address_space(3))) void*)l, 16, 0, 0);
}

// ---------------------------------------------------------------------------
// prep: grid 2560.
//   blocks 0..1535:   fp32->bf16 casts, 8 x (256x8-elem) units per block
//   blocks 1536..2559: 4 weight transposes, 64x64 tiles
// ---------------------------------------------------------------------------
__global__ __launch_bounds__(256) void prep(
    const float* __restrict__ qsrc, const float* __restrict__ ksrc,
    const float* __restrict__ vsrc,
    const float* __restrict__ w0, const float* __restrict__ w1,
    const float* __restrict__ w2, const float* __restrict__ w3,
    __bf16* __restrict__ qdst, __bf16* __restrict__ kdst,
    __bf16* __restrict__ vdst,
    __bf16* __restrict__ t0, __bf16* __restrict__ t1,
    __bf16* __restrict__ t2, __bf16* __restrict__ t3) {
  constexpr int STR = 72;
  __shared__ __bf16 sh[64 * STR];
  int bx = blockIdx.x, tid = threadIdx.x;
  if (bx < 1536) {
    int z = bx >> 9, ib = bx & 511;
    const float* src = z == 0 ? qsrc : z == 1 ? ksrc : vsrc;
    __bf16* dst = z == 0 ? qdst : z == 1 ? kdst : vdst;
#pragma unroll
    for (int k = 0; k < 8; ++k) {
      int u = ib * 2048 + k * 256 + tid;           // 8-elem unit
      const float4* s = (const float4*)src + (size_t)u * 2;
      float4 f0 = s[0], f1 = s[1];
      v8bf v;
      v[0] = (__bf16)f0.x; v[1] = (__bf16)f0.y; v[2] = (__bf16)f0.z; v[3] = (__bf16)f0.w;
      v[4] = (__bf16)f1.x; v[5] = (__bf16)f1.y; v[6] = (__bf16)f1.z; v[7] = (__bf16)f1.w;
      *(v8bf*)(dst + (size_t)u * 8) = v;
    }
  } else {
    int idx = bx - 1536;
    int z = idx >> 8;
    const float* W = z == 0 ? w0 : z == 1 ? w1 : z == 2 ? w2 : w3;
    __bf16* Wt = z == 0 ? t0 : z == 1 ? t1 : z == 2 ? t2 : t3;
    int n0 = (idx & 15) * 64, k0 = ((idx >> 4) & 15) * 64;
#pragma unroll
    for (int p = 0; p < 4; ++p) {
      int c = tid + p * 256;
      int r = c >> 4, off = (c & 15) * 4;
      float4 f = *(const float4*)(W + (size_t)(k0 + r) * DD + n0 + off);
      __bf16* d = &sh[r * STR + off];
      d[0] = (__bf16)f.x; d[1] = (__bf16)f.y; d[2] = (__bf16)f.z; d[3] = (__bf16)f.w;
    }
    __syncthreads();
#pragma unroll
    for (int p = 0; p < 2; ++p) {
      int c = tid + p * 256;
      int nr = c >> 3, koff = (c & 7) * 8;
      v8bf v;
#pragma unroll
      for (int j = 0; j < 8; ++j) v[j] = sh[(koff + j) * STR + nr];
      *(v8bf*)(Wt + (size_t)(n0 + nr) * DD + k0 + koff) = v;
    }
  }
}

// ---------------------------------------------------------------------------
// Shared GEMM mainloop: acc[4][4] += A-tile(m0) @ Wt-tile(n0)^T over K=1024.
// (proven R0/R4 structure — every structural variant tried in R1/R2/R5 lost)
// ---------------------------------------------------------------------------
__device__ __forceinline__ void gemm_core(const __bf16* __restrict__ A,
                                          const __bf16* __restrict__ Wt,
                                          int m0, int n0,
                                          __bf16* ash, __bf16* bsh,
                                          int wave, int lane, int quad, int l15,
                                          v4f acc[4][4]) {
  int wm = (wave & 1) * 64, wn = (wave >> 1) * 64;
  for (int k0 = 0; k0 < DD; k0 += 64) {
    __syncthreads();
#pragma unroll
    for (int i = 0; i < 4; ++i) {
      int c = wave * 256 + i * 64 + lane;
      int row = c >> 3, g = (c & 7) ^ (row & 7);
      gl2lds16(A + (size_t)(m0 + row) * DD + k0 + g * 8, ash + wave * 2048 + i * 512);
      gl2lds16(Wt + (size_t)(n0 + row) * DD + k0 + g * 8, bsh + wave * 2048 + i * 512);
    }
    __syncthreads();
#pragma unroll
    for (int ks = 0; ks < 2; ++ks) {
      int sw = (((ks * 4 + quad) ^ (l15 & 7))) * 8;
      v8bf a[4], b[4];
#pragma unroll
      for (int jm = 0; jm < 4; ++jm) a[jm] = *(v8bf*)&ash[(wm + jm * 16 + l15) * 64 + sw];
#pragma unroll
      for (int jn = 0; jn < 4; ++jn) b[jn] = *(v8bf*)&bsh[(wn + jn * 16 + l15) * 64 + sw];
#pragma unroll
      for (int jm = 0; jm < 4; ++jm)
#pragma unroll
        for (int jn = 0; jn < 4; ++jn)
          acc[jm][jn] = __builtin_amdgcn_mfma_f32_16x16x32_bf16(a[jm], b[jn], acc[jm][jn], 0, 0, 0);
    }
  }
}

// XCD-aware tile swizzle: the 8 blocks sharing an m-panel get lin%8==c -> one XCD.
__device__ __forceinline__ void swz_tiles(int& m0, int& n0) {
  int lin = blockIdx.x + 8 * blockIdx.y;
  int c = lin & 7, t = lin >> 3;
  n0 = (t & 7) * 128;
  m0 = (c + ((t >> 3) << 3)) * 128;
}

// ---------------------------------------------------------------------------
// Fused Q/K/V projection GEMMs. grid (8,64,3).  (verbatim R4)
// ---------------------------------------------------------------------------
__global__ __launch_bounds__(256) void gemm_qkv(
    const __bf16* __restrict__ Qc, const __bf16* __restrict__ Kc,
    const __bf16* __restrict__ Vc,
    const __bf16* __restrict__ wqT, const __bf16* __restrict__ wkT,
    const __bf16* __restrict__ wvT,
    const float* __restrict__ qb, const float* __restrict__ kb,
    const float* __restrict__ vb,
    __bf16* __restrict__ Qp, __bf16* __restrict__ Kp, __bf16* __restrict__ VTb) {
  __shared__ __bf16 ash[128 * 64];
  __shared__ __bf16 bsh[128 * 64];
  int z = blockIdx.z;
  const __bf16* A  = z == 0 ? Qc : z == 1 ? Kc : Vc;
  const __bf16* Wt = z == 0 ? wqT : z == 1 ? wkT : wvT;
  const float* bias = z == 0 ? qb : z == 1 ? kb : vb;
  int tid = threadIdx.x, wave = tid >> 6, lane = tid & 63;
  int quad = lane >> 4, l15 = lane & 15;
  int m0, n0;
  swz_tiles(m0, n0);
  int wm = (wave & 1) * 64, wn = (wave >> 1) * 64;
  v4f acc[4][4];
#pragma unroll
  for (int jm = 0; jm < 4; ++jm)
#pragma unroll
    for (int jn = 0; jn < 4; ++jn) acc[jm][jn] = (v4f){0.f, 0.f, 0.f, 0.f};

  gemm_core(A, Wt, m0, n0, ash, bsh, wave, lane, quad, l15, acc);

  if (z == 2) {
    int b = m0 >> 11;
    int tbase = (m0 & 2047) + wm;
#pragma unroll
    for (int jn = 0; jn < 4; ++jn) {
      int col = n0 + wn + jn * 16 + l15;   // = h*64 + d
      float bv = bias[col];
      __bf16* rowp = VTb + ((size_t)(b * 16 + (col >> 6)) * 64 + (col & 63)) * TT;
#pragma unroll
      for (int jm = 0; jm < 4; ++jm) {
        v4bf o;
#pragma unroll
        for (int r = 0; r < 4; ++r) o[r] = (__bf16)(acc[jm][jn][r] + bv);
        *(v4bf*)(rowp + tbase + jm * 16 + quad * 4) = o;
      }
    }
  } else {
    __bf16* C = z == 0 ? Qp : Kp;
    float scale = z == 0 ? C2SCALE : 1.0f;
#pragma unroll
    for (int jn = 0; jn < 4; ++jn) {
      int col = n0 + wn + jn * 16 + l15;
      float bv = bias[col];
#pragma unroll
      for (int jm = 0; jm < 4; ++jm) {
#pragma unroll
        for (int r = 0; r < 4; ++r) {
          int row = m0 + wm + jm * 16 + quad * 4 + r;
          C[(size_t)row * DD + col] = (__bf16)((acc[jm][jn][r] + bv) * scale);
        }
      }
    }
  }
}

// ---------------------------------------------------------------------------
// Output GEMM: out = Ab @ woT^T + wo_b (fp32). grid (8,64).  (verbatim R4)
// ---------------------------------------------------------------------------
__global__ __launch_bounds__(256) void gemm_out(const __bf16* __restrict__ A,
                                                const __bf16* __restrict__ Wt,
                                                const float* __restrict__ bias,
                                                float* __restrict__ C) {
  __shared__ __bf16 ash[128 * 64];
  __shared__ __bf16 bsh[128 * 64];
  int tid = threadIdx.x, wave = tid >> 6, lane = tid & 63;
  int quad = lane >> 4, l15 = lane & 15;
  int m0, n0;
  swz_tiles(m0, n0);
  int wm = (wave & 1) * 64, wn = (wave >> 1) * 64;
  v4f acc[4][4];
#pragma unroll
  for (int jm = 0; jm < 4; ++jm)
#pragma unroll
    for (int jn = 0; jn < 4; ++jn) acc[jm][jn] = (v4f){0.f, 0.f, 0.f, 0.f};

  gemm_core(A, Wt, m0, n0, ash, bsh, wave, lane, quad, l15, acc);

#pragma unroll
  for (int jn = 0; jn < 4; ++jn) {
    int col = n0 + wn + jn * 16 + l15;
    float bv = bias[col];
#pragma unroll
    for (int jm = 0; jm < 4; ++jm) {
#pragma unroll
      for (int r = 0; r < 4; ++r) {
        int row = m0 + wm + jm * 16 + quad * 4 + r;
        C[(size_t)row * DD + col] = acc[jm][jn][r] + bv;
      }
    }
  }
}

// ---------------------------------------------------------------------------
// Flash attention (causal), transposed-softmax, balanced pairing, XCD head
// placement, lr via ones-MFMA, setprio (all proven R4).
// NEW: TRIPLE-buffered K/V with 2-deep prefetch + counted vmcnt(4) at raw
// s_barrier (T4).  The old __syncthreads() emitted a full vmcnt(0) drain per
// k-tile, stalling on the in-flight prefetch with only 2 blocks/CU to hide
// it.  Ledger (per wave, 4 loads/stage): after prologue vmcnt(4) -> {t1}.
// At tile kt: stage t(kt+2) (+4) -> {t(kt+1), t(kt+2)}; end-of-tile vmcnt(4)
// lands t(kt+1) exactly, t(kt+2) stays in flight.  Tail: vmcnt(0).
// psh is wave-private (Q rows + P^T rows wave*32..+31) -> no cross-wave
// lgkm hazard; ksh/vsh visibility = per-wave vmcnt + barrier.
// LDS 64KB -> still 2 blocks/CU (grid 512 = 2/CU).  grid: (8, 64)
// ---------------------------------------------------------------------------
__global__ __launch_bounds__(256) void attn_bal(const __bf16* __restrict__ Q,
                                                const __bf16* __restrict__ K,
                                                const __bf16* __restrict__ VT,
                                                __bf16* __restrict__ O) {
  __shared__ __bf16 ksh[3][64 * 64];
  __shared__ __bf16 vsh[3][64 * 64];       // vsh[d][t]
  __shared__ __bf16 psh[128 * 64];         // Q staging / P^T, XOR-swizzled
  int tid = threadIdx.x, wave = tid >> 6, lane = tid & 63;
  int quad = lane >> 4, l15 = lane & 15;
  int swz = l15 & 7;
  int lin = blockIdx.x + 8 * blockIdx.y;
  int c = lin & 7, t = lin >> 3;
  int xq = t & 7;                     // q-pair index 0..7
  int bh = c + ((t >> 3) << 3);       // head-group 0..63
  int b = bh >> 4, h = bh & 15;
  const __bf16* Qb = Q + (size_t)(b * TT) * DD + h * HDIM;
  const __bf16* Kb = K + (size_t)(b * TT) * DD + h * HDIM;
  const __bf16* Vb = VT + (size_t)bh * HDIM * TT;
  __bf16* Ob = O + (size_t)(b * TT) * DD + h * HDIM;

  v8bf ones;
#pragma unroll
  for (int j = 0; j < 8; ++j) ones[j] = (__bf16)1.0f;

  for (int phase = 0; phase < 2; ++phase) {
    int qi = phase ? 15 - xq : xq;
    int q0 = qi * 128;
    int ktiles = 2 * qi + 2;

    // stage this wave's own Q rows (wave-private psh region)
#pragma unroll
    for (int i = 0; i < 4; ++i) {
      int cc = wave * 256 + i * 64 + lane;
      int row = cc >> 3, g = (cc & 7) ^ (row & 7);
      gl2lds16(Qb + (size_t)(q0 + row) * DD + g * 8, psh + wave * 2048 + i * 512);
    }
    // stage k-tiles 0 and 1 (ktiles >= 2 always)
#pragma unroll
    for (int tt = 0; tt < 2; ++tt) {
      int k0s = tt * 64;
#pragma unroll
      for (int i = 0; i < 2; ++i) {
        int cc = wave * 128 + i * 64 + lane;
        int row = cc >> 3, g = (cc & 7) ^ (row & 7);
        gl2lds16(Kb + (size_t)(k0s + row) * DD + g * 8, &ksh[tt][wave * 1024 + i * 512]);
        gl2lds16(Vb + (size_t)row * TT + k0s + g * 8, &vsh[tt][wave * 1024 + i * 512]);
      }
    }
    // lands Q(4)+tile0(4); tile1's 4 stay in flight
    asm volatile("s_waitcnt vmcnt(4)" ::: "memory");
    __builtin_amdgcn_s_barrier();

    // hoist Q fragments (B-operand) for the entire k-loop
    v8bf qf[2][2];
#pragma unroll
    for (int set = 0; set < 2; ++set)
#pragma unroll
      for (int ks = 0; ks < 2; ++ks)
        qf[set][ks] = *(v8bf*)&psh[(wave * 32 + set * 16 + l15) * 64 + ((ks * 4 + quad) ^ swz) * 8];

    int qg[2] = {q0 + wave * 32 + l15, q0 + wave * 32 + 16 + l15};
    v4f oacc[2][4], lracc[2];
#pragma unroll
    for (int set = 0; set < 2; ++set) {
      lracc[set] = (v4f){0.f, 0.f, 0.f, 0.f};
#pragma unroll
      for (int jm = 0; jm < 4; ++jm) oacc[set][jm] = (v4f){0.f, 0.f, 0.f, 0.f};
    }

    int cur = 0;
    for (int kt = 0; kt < ktiles; ++kt) {
      bool morestage = (kt + 2 < ktiles);   // block-uniform
      if (morestage) {
        int tb = cur + 2; if (tb >= 3) tb -= 3;
        int k0n = (kt + 2) * 64;
#pragma unroll
        for (int i = 0; i < 2; ++i) {
          int cc = wave * 128 + i * 64 + lane;
          int row = cc >> 3, g = (cc & 7) ^ (row & 7);
          gl2lds16(Kb + (size_t)(k0n + row) * DD + g * 8, &ksh[tb][wave * 1024 + i * 512]);
          gl2lds16(Vb + (size_t)row * TT + k0n + g * 8, &vsh[tb][wave * 1024 + i * 512]);
        }
      }
      int k0 = kt * 64;
      const __bf16* kshp = &ksh[cur][0];
      const __bf16* vshp = &vsh[cur][0];

      // S^T = K (C2*Q)^T
      v4f s[2][4];
#pragma unroll
      for (int set = 0; set < 2; ++set)
#pragma unroll
        for (int jf = 0; jf < 4; ++jf) s[set][jf] = (v4f){0.f, 0.f, 0.f, 0.f};
      __builtin_amdgcn_s_setprio(1);
#pragma unroll
      for (int ks = 0; ks < 2; ++ks) {
        int sw = ((ks * 4 + quad) ^ swz) * 8;
#pragma unroll
        for (int jf = 0; jf < 4; ++jf) {
          v8bf kf = *(v8bf*)&kshp[(jf * 16 + l15) * 64 + sw];
          s[0][jf] = __builtin_amdgcn_mfma_f32_16x16x32_bf16(kf, qf[0][ks], s[0][jf], 0, 0, 0);
          s[1][jf] = __builtin_amdgcn_mfma_f32_16x16x32_bf16(kf, qf[1][ks], s[1][jf], 0, 0, 0);
        }
      }
      __builtin_amdgcn_s_setprio(0);

      bool diag = (kt >= 2 * qi);
#pragma unroll
      for (int set = 0; set < 2; ++set) {
        int qrow = wave * 32 + set * 16 + l15;
        __bf16* prow = &psh[qrow * 64];
#pragma unroll
        for (int jf = 0; jf < 4; ++jf) {
          v4bf pk;
#pragma unroll
          for (int r = 0; r < 4; ++r) {
            float p = __builtin_amdgcn_exp2f(s[set][jf][r]);
            if (diag) {
              int kg = k0 + jf * 16 + quad * 4 + r;
              if (kg > qg[set]) p = 0.f;
            }
            pk[r] = (__bf16)p;
          }
          int chunk = jf * 2 + (quad >> 1);
          *(v4bf*)&prow[(chunk ^ swz) * 8 + (quad & 1) * 4] = pk;
        }
      }

      // O^T += V^T P^T ; lr += ones @ P^T (row sums, all lanes get full sum)
      __builtin_amdgcn_s_setprio(1);
#pragma unroll
      for (int ks = 0; ks < 2; ++ks) {
        int sw = ((ks * 4 + quad) ^ swz) * 8;
        v8bf pb0 = *(v8bf*)&psh[(wave * 32 + l15) * 64 + sw];
        v8bf pb1 = *(v8bf*)&psh[(wave * 32 + 16 + l15) * 64 + sw];
        lracc[0] = __builtin_amdgcn_mfma_f32_16x16x32_bf16(ones, pb0, lracc[0], 0, 0, 0);
        lracc[1] = __builtin_amdgcn_mfma_f32_16x16x32_bf16(ones, pb1, lracc[1], 0, 0, 0);
#pragma unroll
        for (int jm = 0; jm < 4; ++jm) {
          v8bf vf = *(v8bf*)&vshp[(jm * 16 + l15) * 64 + sw];
          oacc[0][jm] = __builtin_amdgcn_mfma_f32_16x16x32_bf16(vf, pb0, oacc[0][jm], 0, 0, 0);
          oacc[1][jm] = __builtin_amdgcn_mfma_f32_16x16x32_bf16(vf, pb1, oacc[1][jm], 0, 0, 0);
        }
      }
      __builtin_amdgcn_s_setprio(0);

      // counted wait: land tile kt+1, keep tile kt+2 in flight (T4)
      if (morestage) {
        asm volatile("s_waitcnt vmcnt(4)" ::: "memory");
      } else {
        asm volatile("s_waitcnt vmcnt(0)" ::: "memory");
      }
      __builtin_amdgcn_s_barrier();
      cur = cur + 1; if (cur >= 3) cur = 0;
    }

    // epilogue: O[q][d] = O^T / lr
#pragma unroll
    for (int set = 0; set < 2; ++set) {
      float inv = 1.0f / lracc[set][0];
      int q = q0 + wave * 32 + set * 16 + l15;
#pragma unroll
      for (int jm = 0; jm < 4; ++jm) {
        v4bf o;
#pragma unroll
        for (int r = 0; r < 4; ++r) o[r] = (__bf16)(oacc[set][jm][r] * inv);
        *(v4bf*)(Ob + (size_t)q * DD + jm * 16 + quad * 4) = o;
      }
    }
  }
}

// ---------------------------------------------------------------------------
extern "C" void kernel_launch(void* const* d_in, const int* in_sizes, int n_in,
                              void* d_out, int out_size, void* d_ws, size_t ws_size,
                              hipStream_t stream) {
  const float* query = (const float*)d_in[0];
  const float* key_  = (const float*)d_in[1];
  const float* value = (const float*)d_in[2];
  const float* wq_w = (const float*)d_in[3];
  const float* wq_b = (const float*)d_in[4];
  const float* wk_w = (const float*)d_in[5];
  const float* wk_b = (const float*)d_in[6];
  const float* wv_w = (const float*)d_in[7];
  const float* wv_b = (const float*)d_in[8];
  const float* wo_w = (const float*)d_in[9];
  const float* wo_b = (const float*)d_in[10];

  char* ws = (char*)d_ws;
  const size_t MB = (size_t)1 << 20;
  __bf16* wqT = (__bf16*)(ws + 0 * MB);
  __bf16* wkT = (__bf16*)(ws + 2 * MB);
  __bf16* wvT = (__bf16*)(ws + 4 * MB);
  __bf16* woT = (__bf16*)(ws + 6 * MB);
  __bf16* Qc  = (__bf16*)(ws + 8 * MB);    // cast inputs (later reused)
  __bf16* Kc  = (__bf16*)(ws + 24 * MB);
  __bf16* Vc  = (__bf16*)(ws + 40 * MB);
  __bf16* Qp  = (__bf16*)(ws + 56 * MB);
  __bf16* Kp  = (__bf16*)(ws + 72 * MB);
  __bf16* VTb = (__bf16*)(ws + 88 * MB);   // peak 104 MB
  __bf16* Ab  = (__bf16*)(ws + 8 * MB);    // reuse Qc
  float* out = (float*)d_out;

  dim3 tb(256);
  prep<<<dim3(2560), tb, 0, stream>>>(query, key_, value, wq_w, wk_w, wv_w, wo_w,
                                      Qc, Kc, Vc, wqT, wkT, wvT, woT);
  gemm_qkv<<<dim3(8, 64, 3), tb, 0, stream>>>(Qc, Kc, Vc, wqT, wkT, wvT,
                                              wq_b, wk_b, wv_b, Qp, Kp, VTb);
  attn_bal<<<dim3(8, 64), tb, 0, stream>>>(Qp, Kp, VTb, Ab);
  gemm_out<<<dim3(8, 64), tb, 0, stream>>>(Ab, woT, wo_b, out);
}

// Round 7
// 305.208 us; speedup vs baseline: 1.1041x; 1.0529x over previous
//
#include <hip/hip_runtime.h>
#include <hip/hip_bf16.h>

#define BB 4
#define TT 2048
#define DD 1024
#define NHEAD 16
#define HDIM 64

typedef __bf16 v8bf __attribute__((ext_vector_type(8)));
typedef __bf16 v4bf __attribute__((ext_vector_type(4)));
typedef float  v4f  __attribute__((ext_vector_type(4)));

// (1/32) * log2(e): folded into Q projection epilogue
#define C2SCALE 0.04508422376f

__device__ __forceinline__ void gl2lds16(const void* g, void* l) {
  __builtin_amdgcn_global_load_lds(
      (__attribute__((address_space(1))) const void*)g,
      (__attribute__((address_space(3))) void*)l, 16, 0, 0);
}

// ---------------------------------------------------------------------------
// prep: grid 2560.  (verbatim R4)
//   blocks 0..1535:   fp32->bf16 casts, 8 x (256x8-elem) units per block
//   blocks 1536..2559: 4 weight transposes, 64x64 tiles
// ---------------------------------------------------------------------------
__global__ __launch_bounds__(256) void prep(
    const float* __restrict__ qsrc, const float* __restrict__ ksrc,
    const float* __restrict__ vsrc,
    const float* __restrict__ w0, const float* __restrict__ w1,
    const float* __restrict__ w2, const float* __restrict__ w3,
    __bf16* __restrict__ qdst, __bf16* __restrict__ kdst,
    __bf16* __restrict__ vdst,
    __bf16* __restrict__ t0, __bf16* __restrict__ t1,
    __bf16* __restrict__ t2, __bf16* __restrict__ t3) {
  constexpr int STR = 72;
  __shared__ __bf16 sh[64 * STR];
  int bx = blockIdx.x, tid = threadIdx.x;
  if (bx < 1536) {
    int z = bx >> 9, ib = bx & 511;
    const float* src = z == 0 ? qsrc : z == 1 ? ksrc : vsrc;
    __bf16* dst = z == 0 ? qdst : z == 1 ? kdst : vdst;
#pragma unroll
    for (int k = 0; k < 8; ++k) {
      int u = ib * 2048 + k * 256 + tid;           // 8-elem unit
      const float4* s = (const float4*)src + (size_t)u * 2;
      float4 f0 = s[0], f1 = s[1];
      v8bf v;
      v[0] = (__bf16)f0.x; v[1] = (__bf16)f0.y; v[2] = (__bf16)f0.z; v[3] = (__bf16)f0.w;
      v[4] = (__bf16)f1.x; v[5] = (__bf16)f1.y; v[6] = (__bf16)f1.z; v[7] = (__bf16)f1.w;
      *(v8bf*)(dst + (size_t)u * 8) = v;
    }
  } else {
    int idx = bx - 1536;
    int z = idx >> 8;
    const float* W = z == 0 ? w0 : z == 1 ? w1 : z == 2 ? w2 : w3;
    __bf16* Wt = z == 0 ? t0 : z == 1 ? t1 : z == 2 ? t2 : t3;
    int n0 = (idx & 15) * 64, k0 = ((idx >> 4) & 15) * 64;
#pragma unroll
    for (int p = 0; p < 4; ++p) {
      int c = tid + p * 256;
      int r = c >> 4, off = (c & 15) * 4;
      float4 f = *(const float4*)(W + (size_t)(k0 + r) * DD + n0 + off);
      __bf16* d = &sh[r * STR + off];
      d[0] = (__bf16)f.x; d[1] = (__bf16)f.y; d[2] = (__bf16)f.z; d[3] = (__bf16)f.w;
    }
    __syncthreads();
#pragma unroll
    for (int p = 0; p < 2; ++p) {
      int c = tid + p * 256;
      int nr = c >> 3, koff = (c & 7) * 8;
      v8bf v;
#pragma unroll
      for (int j = 0; j < 8; ++j) v[j] = sh[(koff + j) * STR + nr];
      *(v8bf*)(Wt + (size_t)(n0 + nr) * DD + k0 + koff) = v;
    }
  }
}

// ---------------------------------------------------------------------------
// Shared GEMM mainloop: acc[4][4] += A-tile(m0) @ Wt-tile(n0)^T over K=1024.
// (proven R0/R4 structure — every structural variant tried in R1/R2/R5 lost)
// ---------------------------------------------------------------------------
__device__ __forceinline__ void gemm_core(const __bf16* __restrict__ A,
                                          const __bf16* __restrict__ Wt,
                                          int m0, int n0,
                                          __bf16* ash, __bf16* bsh,
                                          int wave, int lane, int quad, int l15,
                                          v4f acc[4][4]) {
  int wm = (wave & 1) * 64, wn = (wave >> 1) * 64;
  for (int k0 = 0; k0 < DD; k0 += 64) {
    __syncthreads();
#pragma unroll
    for (int i = 0; i < 4; ++i) {
      int c = wave * 256 + i * 64 + lane;
      int row = c >> 3, g = (c & 7) ^ (row & 7);
      gl2lds16(A + (size_t)(m0 + row) * DD + k0 + g * 8, ash + wave * 2048 + i * 512);
      gl2lds16(Wt + (size_t)(n0 + row) * DD + k0 + g * 8, bsh + wave * 2048 + i * 512);
    }
    __syncthreads();
#pragma unroll
    for (int ks = 0; ks < 2; ++ks) {
      int sw = (((ks * 4 + quad) ^ (l15 & 7))) * 8;
      v8bf a[4], b[4];
#pragma unroll
      for (int jm = 0; jm < 4; ++jm) a[jm] = *(v8bf*)&ash[(wm + jm * 16 + l15) * 64 + sw];
#pragma unroll
      for (int jn = 0; jn < 4; ++jn) b[jn] = *(v8bf*)&bsh[(wn + jn * 16 + l15) * 64 + sw];
#pragma unroll
      for (int jm = 0; jm < 4; ++jm)
#pragma unroll
        for (int jn = 0; jn < 4; ++jn)
          acc[jm][jn] = __builtin_amdgcn_mfma_f32_16x16x32_bf16(a[jm], b[jn], acc[jm][jn], 0, 0, 0);
    }
  }
}

// XCD-aware tile swizzle: the 8 blocks sharing an m-panel get lin%8==c -> one XCD.
__device__ __forceinline__ void swz_tiles(int& m0, int& n0) {
  int lin = blockIdx.x + 8 * blockIdx.y;
  int c = lin & 7, t = lin >> 3;
  n0 = (t & 7) * 128;
  m0 = (c + ((t >> 3) << 3)) * 128;
}

// ---------------------------------------------------------------------------
// Fused Q/K/V projection GEMMs. grid (8,64,3).  (verbatim R4)
// ---------------------------------------------------------------------------
__global__ __launch_bounds__(256) void gemm_qkv(
    const __bf16* __restrict__ Qc, const __bf16* __restrict__ Kc,
    const __bf16* __restrict__ Vc,
    const __bf16* __restrict__ wqT, const __bf16* __restrict__ wkT,
    const __bf16* __restrict__ wvT,
    const float* __restrict__ qb, const float* __restrict__ kb,
    const float* __restrict__ vb,
    __bf16* __restrict__ Qp, __bf16* __restrict__ Kp, __bf16* __restrict__ VTb) {
  __shared__ __bf16 ash[128 * 64];
  __shared__ __bf16 bsh[128 * 64];
  int z = blockIdx.z;
  const __bf16* A  = z == 0 ? Qc : z == 1 ? Kc : Vc;
  const __bf16* Wt = z == 0 ? wqT : z == 1 ? wkT : wvT;
  const float* bias = z == 0 ? qb : z == 1 ? kb : vb;
  int tid = threadIdx.x, wave = tid >> 6, lane = tid & 63;
  int quad = lane >> 4, l15 = lane & 15;
  int m0, n0;
  swz_tiles(m0, n0);
  int wm = (wave & 1) * 64, wn = (wave >> 1) * 64;
  v4f acc[4][4];
#pragma unroll
  for (int jm = 0; jm < 4; ++jm)
#pragma unroll
    for (int jn = 0; jn < 4; ++jn) acc[jm][jn] = (v4f){0.f, 0.f, 0.f, 0.f};

  gemm_core(A, Wt, m0, n0, ash, bsh, wave, lane, quad, l15, acc);

  if (z == 2) {
    int b = m0 >> 11;
    int tbase = (m0 & 2047) + wm;
#pragma unroll
    for (int jn = 0; jn < 4; ++jn) {
      int col = n0 + wn + jn * 16 + l15;   // = h*64 + d
      float bv = bias[col];
      __bf16* rowp = VTb + ((size_t)(b * 16 + (col >> 6)) * 64 + (col & 63)) * TT;
#pragma unroll
      for (int jm = 0; jm < 4; ++jm) {
        v4bf o;
#pragma unroll
        for (int r = 0; r < 4; ++r) o[r] = (__bf16)(acc[jm][jn][r] + bv);
        *(v4bf*)(rowp + tbase + jm * 16 + quad * 4) = o;
      }
    }
  } else {
    __bf16* C = z == 0 ? Qp : Kp;
    float scale = z == 0 ? C2SCALE : 1.0f;
#pragma unroll
    for (int jn = 0; jn < 4; ++jn) {
      int col = n0 + wn + jn * 16 + l15;
      float bv = bias[col];
#pragma unroll
      for (int jm = 0; jm < 4; ++jm) {
#pragma unroll
        for (int r = 0; r < 4; ++r) {
          int row = m0 + wm + jm * 16 + quad * 4 + r;
          C[(size_t)row * DD + col] = (__bf16)((acc[jm][jn][r] + bv) * scale);
        }
      }
    }
  }
}

// ---------------------------------------------------------------------------
// Output GEMM: out = Ab @ woT^T + wo_b (fp32). grid (8,64).  (verbatim R4)
// ---------------------------------------------------------------------------
__global__ __launch_bounds__(256) void gemm_out(const __bf16* __restrict__ A,
                                                const __bf16* __restrict__ Wt,
                                                const float* __restrict__ bias,
                                                float* __restrict__ C) {
  __shared__ __bf16 ash[128 * 64];
  __shared__ __bf16 bsh[128 * 64];
  int tid = threadIdx.x, wave = tid >> 6, lane = tid & 63;
  int quad = lane >> 4, l15 = lane & 15;
  int m0, n0;
  swz_tiles(m0, n0);
  int wm = (wave & 1) * 64, wn = (wave >> 1) * 64;
  v4f acc[4][4];
#pragma unroll
  for (int jm = 0; jm < 4; ++jm)
#pragma unroll
    for (int jn = 0; jn < 4; ++jn) acc[jm][jn] = (v4f){0.f, 0.f, 0.f, 0.f};

  gemm_core(A, Wt, m0, n0, ash, bsh, wave, lane, quad, l15, acc);

#pragma unroll
  for (int jn = 0; jn < 4; ++jn) {
    int col = n0 + wn + jn * 16 + l15;
    float bv = bias[col];
#pragma unroll
    for (int jm = 0; jm < 4; ++jm) {
#pragma unroll
      for (int r = 0; r < 4; ++r) {
        int row = m0 + wm + jm * 16 + quad * 4 + r;
        C[(size_t)row * DD + col] = acc[jm][jn][r] + bv;
      }
    }
  }
}

// ---------------------------------------------------------------------------
// Flash attention (causal), transposed-softmax, no running max, lr via
// ones-MFMA, setprio, dbuf K/V (ALL the R4-proven k-loop body).
// NEW: fine-grained work split — ONE q-tile per block, grid (8,128) = 1024
// blocks -> 3 blocks/CU resident (48KB LDS x3 = 144KB <= 160KB) vs the old
// 512-block balanced pairing pinned at 2/CU.  More waves/SIMD to hide the
// serial QK^T->exp->P-write->P-read->PV chain; dynamic packing replaces
// static pairing.  Long blocks (qi=15: 32 k-tiles) launch FIRST via
// qi = 15-(by>>3).  XCD affinity preserved: bh = c + 8*(by&7) keeps all 16
// q-tiles of a head on one XCD (8 heads/XCD = 4MB K+V in L2, as before).
// ---------------------------------------------------------------------------
__global__ __launch_bounds__(256) void attn_bal(const __bf16* __restrict__ Q,
                                                const __bf16* __restrict__ K,
                                                const __bf16* __restrict__ VT,
                                                __bf16* __restrict__ O) {
  __shared__ __bf16 ksh[2][64 * 64];
  __shared__ __bf16 vsh[2][64 * 64];       // vsh[d][t]
  __shared__ __bf16 psh[128 * 64];         // Q staging / P^T, XOR-swizzled
  int tid = threadIdx.x, wave = tid >> 6, lane = tid & 63;
  int quad = lane >> 4, l15 = lane & 15;
  int swz = l15 & 7;
  int c = blockIdx.x;                 // XCD slot 0..7
  int by = blockIdx.y;                // 0..127
  int bh = c + 8 * (by & 7);          // head-group 0..63
  int qi = 15 - (by >> 3);            // q-tile 15..0 (longest first)
  int b = bh >> 4, h = bh & 15;
  const __bf16* Qb = Q + (size_t)(b * TT) * DD + h * HDIM;
  const __bf16* Kb = K + (size_t)(b * TT) * DD + h * HDIM;
  const __bf16* Vb = VT + (size_t)bh * HDIM * TT;
  __bf16* Ob = O + (size_t)(b * TT) * DD + h * HDIM;

  v8bf ones;
#pragma unroll
  for (int j = 0; j < 8; ++j) ones[j] = (__bf16)1.0f;

  int q0 = qi * 128;
  int ktiles = 2 * qi + 2;

  // stage this wave's own Q rows (wave-private psh region)
#pragma unroll
  for (int i = 0; i < 4; ++i) {
    int cc = wave * 256 + i * 64 + lane;
    int row = cc >> 3, g = (cc & 7) ^ (row & 7);
    gl2lds16(Qb + (size_t)(q0 + row) * DD + g * 8, psh + wave * 2048 + i * 512);
  }
  // stage k-tile 0 into buffer 0
#pragma unroll
  for (int i = 0; i < 2; ++i) {
    int cc = wave * 128 + i * 64 + lane;
    int row = cc >> 3, g = (cc & 7) ^ (row & 7);
    gl2lds16(Kb + (size_t)row * DD + g * 8, &ksh[0][wave * 1024 + i * 512]);
    gl2lds16(Vb + (size_t)row * TT + g * 8, &vsh[0][wave * 1024 + i * 512]);
  }
  __builtin_amdgcn_s_waitcnt(0);
  __syncthreads();

  // hoist Q fragments (B-operand) for the entire k-loop
  v8bf qf[2][2];
#pragma unroll
  for (int set = 0; set < 2; ++set)
#pragma unroll
    for (int ks = 0; ks < 2; ++ks)
      qf[set][ks] = *(v8bf*)&psh[(wave * 32 + set * 16 + l15) * 64 + ((ks * 4 + quad) ^ swz) * 8];

  int qg[2] = {q0 + wave * 32 + l15, q0 + wave * 32 + 16 + l15};
  v4f oacc[2][4], lracc[2];
#pragma unroll
  for (int set = 0; set < 2; ++set) {
    lracc[set] = (v4f){0.f, 0.f, 0.f, 0.f};
#pragma unroll
    for (int jm = 0; jm < 4; ++jm) oacc[set][jm] = (v4f){0.f, 0.f, 0.f, 0.f};
  }

  int pbuf = 0;
  for (int kt = 0; kt < ktiles; ++kt) {
    // prefetch next k-tile into the other buffer; completes during compute
    if (kt + 1 < ktiles) {
      int k0n = (kt + 1) * 64;
#pragma unroll
      for (int i = 0; i < 2; ++i) {
        int cc = wave * 128 + i * 64 + lane;
        int row = cc >> 3, g = (cc & 7) ^ (row & 7);
        gl2lds16(Kb + (size_t)(k0n + row) * DD + g * 8, &ksh[pbuf ^ 1][wave * 1024 + i * 512]);
        gl2lds16(Vb + (size_t)row * TT + k0n + g * 8, &vsh[pbuf ^ 1][wave * 1024 + i * 512]);
      }
    }
    int k0 = kt * 64;
    const __bf16* kshp = &ksh[pbuf][0];
    const __bf16* vshp = &vsh[pbuf][0];

    // S^T = K (C2*Q)^T
    v4f s[2][4];
#pragma unroll
    for (int set = 0; set < 2; ++set)
#pragma unroll
      for (int jf = 0; jf < 4; ++jf) s[set][jf] = (v4f){0.f, 0.f, 0.f, 0.f};
    __builtin_amdgcn_s_setprio(1);
#pragma unroll
    for (int ks = 0; ks < 2; ++ks) {
      int sw = ((ks * 4 + quad) ^ swz) * 8;
#pragma unroll
      for (int jf = 0; jf < 4; ++jf) {
        v8bf kf = *(v8bf*)&kshp[(jf * 16 + l15) * 64 + sw];
        s[0][jf] = __builtin_amdgcn_mfma_f32_16x16x32_bf16(kf, qf[0][ks], s[0][jf], 0, 0, 0);
        s[1][jf] = __builtin_amdgcn_mfma_f32_16x16x32_bf16(kf, qf[1][ks], s[1][jf], 0, 0, 0);
      }
    }
    __builtin_amdgcn_s_setprio(0);

    bool diag = (kt >= 2 * qi);
#pragma unroll
    for (int set = 0; set < 2; ++set) {
      int qrow = wave * 32 + set * 16 + l15;
      __bf16* prow = &psh[qrow * 64];
#pragma unroll
      for (int jf = 0; jf < 4; ++jf) {
        v4bf pk;
#pragma unroll
        for (int r = 0; r < 4; ++r) {
          float p = __builtin_amdgcn_exp2f(s[set][jf][r]);
          if (diag) {
            int kg = k0 + jf * 16 + quad * 4 + r;
            if (kg > qg[set]) p = 0.f;
          }
          pk[r] = (__bf16)p;
        }
        int chunk = jf * 2 + (quad >> 1);
        *(v4bf*)&prow[(chunk ^ swz) * 8 + (quad & 1) * 4] = pk;
      }
    }

    // O^T += V^T P^T ; lr += ones @ P^T (row sums, all lanes get full sum)
    __builtin_amdgcn_s_setprio(1);
#pragma unroll
    for (int ks = 0; ks < 2; ++ks) {
      int sw = ((ks * 4 + quad) ^ swz) * 8;
      v8bf pb0 = *(v8bf*)&psh[(wave * 32 + l15) * 64 + sw];
      v8bf pb1 = *(v8bf*)&psh[(wave * 32 + 16 + l15) * 64 + sw];
      lracc[0] = __builtin_amdgcn_mfma_f32_16x16x32_bf16(ones, pb0, lracc[0], 0, 0, 0);
      lracc[1] = __builtin_amdgcn_mfma_f32_16x16x32_bf16(ones, pb1, lracc[1], 0, 0, 0);
#pragma unroll
      for (int jm = 0; jm < 4; ++jm) {
        v8bf vf = *(v8bf*)&vshp[(jm * 16 + l15) * 64 + sw];
        oacc[0][jm] = __builtin_amdgcn_mfma_f32_16x16x32_bf16(vf, pb0, oacc[0][jm], 0, 0, 0);
        oacc[1][jm] = __builtin_amdgcn_mfma_f32_16x16x32_bf16(vf, pb1, oacc[1][jm], 0, 0, 0);
      }
    }
    __builtin_amdgcn_s_setprio(0);

    __builtin_amdgcn_s_waitcnt(0);   // own next-tile DMA long since done
    __syncthreads();
    pbuf ^= 1;
  }

  // epilogue: O[q][d] = O^T / lr
#pragma unroll
  for (int set = 0; set < 2; ++set) {
    float inv = 1.0f / lracc[set][0];
    int q = q0 + wave * 32 + set * 16 + l15;
#pragma unroll
    for (int jm = 0; jm < 4; ++jm) {
      v4bf o;
#pragma unroll
      for (int r = 0; r < 4; ++r) o[r] = (__bf16)(oacc[set][jm][r] * inv);
      *(v4bf*)(Ob + (size_t)q * DD + jm * 16 + quad * 4) = o;
    }
  }
}

// ---------------------------------------------------------------------------
extern "C" void kernel_launch(void* const* d_in, const int* in_sizes, int n_in,
                              void* d_out, int out_size, void* d_ws, size_t ws_size,
                              hipStream_t stream) {
  const float* query = (const float*)d_in[0];
  const float* key_  = (const float*)d_in[1];
  const float* value = (const float*)d_in[2];
  const float* wq_w = (const float*)d_in[3];
  const float* wq_b = (const float*)d_in[4];
  const float* wk_w = (const float*)d_in[5];
  const float* wk_b = (const float*)d_in[6];
  const float* wv_w = (const float*)d_in[7];
  const float* wv_b = (const float*)d_in[8];
  const float* wo_w = (const float*)d_in[9];
  const float* wo_b = (const float*)d_in[10];

  char* ws = (char*)d_ws;
  const size_t MB = (size_t)1 << 20;
  __bf16* wqT = (__bf16*)(ws + 0 * MB);
  __bf16* wkT = (__bf16*)(ws + 2 * MB);
  __bf16* wvT = (__bf16*)(ws + 4 * MB);
  __bf16* woT = (__bf16*)(ws + 6 * MB);
  __bf16* Qc  = (__bf16*)(ws + 8 * MB);    // cast inputs (later reused)
  __bf16* Kc  = (__bf16*)(ws + 24 * MB);
  __bf16* Vc  = (__bf16*)(ws + 40 * MB);
  __bf16* Qp  = (__bf16*)(ws + 56 * MB);
  __bf16* Kp  = (__bf16*)(ws + 72 * MB);
  __bf16* VTb = (__bf16*)(ws + 88 * MB);   // peak 104 MB
  __bf16* Ab  = (__bf16*)(ws + 8 * MB);    // reuse Qc
  float* out = (float*)d_out;

  dim3 tb(256);
  prep<<<dim3(2560), tb, 0, stream>>>(query, key_, value, wq_w, wk_w, wv_w, wo_w,
                                      Qc, Kc, Vc, wqT, wkT, wvT, woT);
  gemm_qkv<<<dim3(8, 64, 3), tb, 0, stream>>>(Qc, Kc, Vc, wqT, wkT, wvT,
                                              wq_b, wk_b, wv_b, Qp, Kp, VTb);
  attn_bal<<<dim3(8, 128), tb, 0, stream>>>(Qp, Kp, VTb, Ab);
  gemm_out<<<dim3(8, 64), tb, 0, stream>>>(Ab, woT, wo_b, out);
}